// Round 5
// baseline (695.461 us; speedup 1.0000x reference)
//
#include <hip/hip_runtime.h>
#include <hip/hip_bf16.h>

using bf16 = __hip_bfloat16;
using short8 = __attribute__((ext_vector_type(8))) short;   // 8 bf16 (4 VGPRs)
using floatx4 = __attribute__((ext_vector_type(4))) float;  // 4 fp32 acc

#define NSEG 4
#define HID 768
#define INDIM 1536
#define NQKV 2304
#define NHEADS 8
#define HD 96

// fp32 -> bf16 bits, round-to-nearest-even
__device__ inline unsigned short f2b(float v) {
  union { float f; unsigned u; } c; c.f = v;
  unsigned r = c.u + 0x7FFF + ((c.u >> 16) & 1);
  return (unsigned short)(r >> 16);
}
// bf16 bits -> fp32
__device__ inline float b2f(unsigned short u) {
  union { unsigned v; float f; } c; c.v = ((unsigned)u) << 16; return c.f;
}

// async global->LDS, 16B per lane: dest = wave-uniform base + lane*16.
__device__ inline void gload16(const void* g, void* l) {
  __builtin_amdgcn_global_load_lds(
      (const __attribute__((address_space(1))) unsigned int*)g,
      (__attribute__((address_space(3))) unsigned int*)l, 16, 0, 0);
}

#define MEMFENCE asm volatile("" ::: "memory")
#define BARRIER do { MEMFENCE; __builtin_amdgcn_s_barrier(); MEMFENCE; } while (0)

// ---------------------------------------------------------------------------
// 8-phase 256x256 GEMM phase body (shared by both GEMMs).
// Expects in scope: lds, lA, lB, acc[8][4], bfr[4][2].
// LDS layout per parity: A at par*65536, B at 32768+par*65536; within a tile:
// [kh][row][32 bf16] (64B rows), st_16x32 swizzle: colbyte ^= 32 when row&8.
// ---------------------------------------------------------------------------
#define PHASE(par, q, LOADB, STAGES, VMW) do {                                 \
    short8 a00 = *(const short8*)(lA + (par)*65536 + (q)*2048);                \
    short8 a01 = *(const short8*)(lA + (par)*65536 + (q)*2048 + 16384);        \
    short8 a10 = *(const short8*)(lA + (par)*65536 + (q)*2048 + 1024);         \
    short8 a11 = *(const short8*)(lA + (par)*65536 + (q)*2048 + 1024 + 16384); \
    if (LOADB) {                                                               \
      _Pragma("unroll")                                                        \
      for (int fn = 0; fn < 4; ++fn) {                                         \
        bfr[fn][0] = *(const short8*)(lB + (par)*65536 + fn*1024);             \
        bfr[fn][1] = *(const short8*)(lB + (par)*65536 + fn*1024 + 16384);     \
      }                                                                        \
    }                                                                          \
    STAGES;                                                                    \
    BARRIER;                                                                   \
    __builtin_amdgcn_s_setprio(1);                                             \
    _Pragma("unroll")                                                          \
    for (int fn = 0; fn < 4; ++fn) {                                           \
      acc[2*(q)][fn]   = __builtin_amdgcn_mfma_f32_16x16x32_bf16(              \
          a00, bfr[fn][0], acc[2*(q)][fn], 0, 0, 0);                           \
      acc[2*(q)][fn]   = __builtin_amdgcn_mfma_f32_16x16x32_bf16(              \
          a01, bfr[fn][1], acc[2*(q)][fn], 0, 0, 0);                           \
      acc[2*(q)+1][fn] = __builtin_amdgcn_mfma_f32_16x16x32_bf16(              \
          a10, bfr[fn][0], acc[2*(q)+1][fn], 0, 0, 0);                         \
      acc[2*(q)+1][fn] = __builtin_amdgcn_mfma_f32_16x16x32_bf16(              \
          a11, bfr[fn][1], acc[2*(q)+1][fn], 0, 0, 0);                         \
    }                                                                          \
    __builtin_amdgcn_s_setprio(0);                                             \
    VMW;                                                                       \
    BARRIER;                                                                   \
  } while (0)

#define VM4 do { asm volatile("s_waitcnt vmcnt(4)" ::: "memory"); } while (0)
#define VM0 do { asm volatile("s_waitcnt vmcnt(0)" ::: "memory"); } while (0)

// ---------------------------------------------------------------------------
// All four weight transposes in ONE launch. z=0..2: Wq/Wk/Wv (1536x768 ->
// 768x1536 at wqkvT+z*HID*INDIM); z=3: Wo (768x1536 -> 1536x768 at woT).
// Grid (48,48,4); out-of-range tiles return.
// ---------------------------------------------------------------------------
__global__ __launch_bounds__(256) void transpose_all(
    const float* __restrict__ Wq, const float* __restrict__ Wk,
    const float* __restrict__ Wv, const float* __restrict__ Wo,
    bf16* __restrict__ wqkvT, bf16* __restrict__ woT) {
  __shared__ unsigned short tile[32][33];
  const int z = blockIdx.z;
  const float* src;
  unsigned short* dst;
  int K, C;
  if (z < 3) {
    src = (z == 0) ? Wq : (z == 1) ? Wk : Wv;
    dst = (unsigned short*)(wqkvT + (size_t)z * HID * INDIM);
    K = INDIM; C = HID;
  } else {
    src = Wo;
    dst = (unsigned short*)woT;
    K = HID; C = INDIM;
  }
  const int c0 = blockIdx.x * 32, k0 = blockIdx.y * 32;
  if (c0 >= C || k0 >= K) return;
  const int tx = threadIdx.x, ty = threadIdx.y;  // 32 x 8
#pragma unroll
  for (int i = 0; i < 4; ++i)
    tile[ty + 8 * i][tx] = f2b(src[(size_t)(k0 + ty + 8 * i) * C + c0 + tx]);
  __syncthreads();
#pragma unroll
  for (int i = 0; i < 4; ++i)
    dst[(size_t)(c0 + ty + 8 * i) * K + k0 + tx] = tile[tx][ty + 8 * i];
}

// ---------------------------------------------------------------------------
// One-time fp32 -> bf16 cast of x (same memory order). 16 elem/thread.
// ---------------------------------------------------------------------------
__global__ __launch_bounds__(256) void convert_x(
    const float* __restrict__ x, bf16* __restrict__ xb) {
  const size_t i = ((size_t)blockIdx.x * 256 + threadIdx.x) * 16;
#pragma unroll
  for (int h = 0; h < 2; ++h) {
    float4 a = *(const float4*)(x + i + 8 * h);
    float4 b = *(const float4*)(x + i + 8 * h + 4);
    union { uint4 u; unsigned short s[8]; } r;
    r.s[0] = f2b(a.x); r.s[1] = f2b(a.y); r.s[2] = f2b(a.z); r.s[3] = f2b(a.w);
    r.s[4] = f2b(b.x); r.s[5] = f2b(b.y); r.s[6] = f2b(b.z); r.s[7] = f2b(b.w);
    *(uint4*)(xb + i + 8 * h) = r.u;
  }
}

// ---------------------------------------------------------------------------
// GEMM1: QKV[m][c] = sum_e A[m][e] * Wqkv[e][c]; 256x256 tile, 8-phase.
// A gathered from bf16 xb (B,T,H,W,D); BK=64 aligns with D=64 (p = kt).
// wT = Wqkv^T [2304][1536] bf16.  (UNCHANGED from round 2 — control.)
// ---------------------------------------------------------------------------
__global__ __launch_bounds__(512, 2) void gemm_qkv(
    const bf16* __restrict__ xb, const bf16* __restrict__ wT,
    bf16* __restrict__ qkv) {
  __shared__ __align__(16) char lds[131072];  // A0|B0|A1|B1, 32KB each
  const int tid = threadIdx.x;
  const int lane = tid & 63, wave = tid >> 6;
  const int wr = wave >> 2, wc = wave & 3;
  const int l15 = lane & 15, quad = lane >> 4;

  // XCD-aware block swizzle: 1152 blocks = 8 XCDs x 144
  const int lt = (blockIdx.x & 7) * 144 + (blockIdx.x >> 3);
  const int n0 = (lt % 9) * 256;
  const int m0 = (lt / 9) * 256;

  // --- staging source precompute (per-lane, kt-invariant) ---
  const int srow = wave * 16 + (lane >> 2);                 // 0..127 in half
  const int dswz = ((lane & 3) * 8) ^ ((lane & 32) >> 1);   // swizzled col
  const bf16* asrc[2];
  const bf16* bsrc[2];
#pragma unroll
  for (int h = 0; h < 2; ++h) {
    const int m = m0 + h * 128 + srow;
    const int r = m >> 2, n = m & 3;
    const int b = r >> 10, hw = r & 1023;
    asrc[h] = xb + ((size_t)((b * 96 + n * 24) * 1024 + hw)) * 64 + dswz;
    bsrc[h] = wT + (size_t)(n0 + h * 128 + srow) * INDIM + dswz;
  }
  char* sdst = lds + wave * 1024;  // wave-uniform LDS stage base

#define STAGE_QA(kt, h) do {                                   \
    char* d_ = sdst + (((kt) & 1) * 65536) + (h) * 8192;       \
    const bf16* s_ = asrc[h] + (size_t)(kt) * 65536;           \
    gload16(s_, d_);                                           \
    gload16(s_ + 32, d_ + 16384);                              \
  } while (0)
#define STAGE_QB(kt, h) do {                                   \
    char* d_ = sdst + 32768 + (((kt) & 1) * 65536) + (h) * 8192; \
    const bf16* s_ = bsrc[h] + (size_t)(kt) * 64;              \
    gload16(s_, d_);                                           \
    gload16(s_ + 32, d_ + 16384);                              \
  } while (0)

  // --- ds_read bases (swizzle is lane-constant: row&8 == l15&8) ---
  const int lofs = l15 * 64 + ((quad * 16) ^ ((l15 & 8) << 2));
  const char* lA = lds + wr * 8192 + lofs;
  const char* lB = lds + 32768 + wc * 4096 + lofs;

  floatx4 acc[8][4] = {};
  short8 bfr[4][2];

  // prologue: K0 fully + K1.B; land K0, keep K1.B in flight
  STAGE_QB(0, 0); STAGE_QB(0, 1); STAGE_QA(0, 0); STAGE_QA(0, 1);
  STAGE_QB(1, 0); STAGE_QB(1, 1);
  VM4;
  BARRIER;

  const int NKT = 24;
  for (int i = 0; i < 12; ++i) {
    const int a = 2 * i;
    PHASE(0, 0, 1, { STAGE_QA(a + 1, 0); }, {});
    PHASE(0, 1, 0, { STAGE_QA(a + 1, 1); }, {});
    PHASE(0, 2, 0, { if (a + 2 < NKT) STAGE_QB(a + 2, 0); }, {});
    PHASE(0, 3, 0, { if (a + 2 < NKT) STAGE_QB(a + 2, 1); },
          { if (a + 2 < NKT) VM4; else VM0; });
    PHASE(1, 0, 1, { if (a + 2 < NKT) STAGE_QA(a + 2, 0); }, {});
    PHASE(1, 1, 0, { if (a + 2 < NKT) STAGE_QA(a + 2, 1); }, {});
    PHASE(1, 2, 0, { if (a + 3 < NKT) STAGE_QB(a + 3, 0); }, {});
    PHASE(1, 3, 0, { if (a + 3 < NKT) STAGE_QB(a + 3, 1); },
          { if (a + 3 < NKT) VM4; else VM0; });
  }
#undef STAGE_QA
#undef STAGE_QB

  // epilogue: C/D layout col=lane&15, row=quad*4+reg
#pragma unroll
  for (int fm = 0; fm < 8; ++fm)
#pragma unroll
    for (int fn = 0; fn < 4; ++fn)
#pragma unroll
      for (int reg = 0; reg < 4; ++reg) {
        const int row = m0 + wr * 128 + fm * 16 + quad * 4 + reg;
        const int col = n0 + wc * 64 + fn * 16 + l15;
        qkv[(size_t)row * NQKV + col] = __float2bfloat16(acc[fm][fn][reg]);
      }
}

// ---------------------------------------------------------------------------
// Attention: one WAVE per row r, pure-register, no LDS. Streamed-q variant:
// only k[4][12] stays resident through the score phase (peak VGPR ~105,
// target 4+ waves/SIMD). hid=768 = 64 lanes x 12 cols; head = 8 lanes.
// ---------------------------------------------------------------------------
__global__ __launch_bounds__(256, 4) void attn_kernel(
    const bf16* __restrict__ qkv, const float* __restrict__ fcos,
    const float* __restrict__ fsin, bf16* __restrict__ obuf) {
  const int wave = threadIdx.x >> 6, lane = threadIdx.x & 63;
  const int r = blockIdx.x * 4 + wave;
  const int c0 = lane * 12;  // column base within hid (even; head = l/8)
  const int j0 = lane * 6;   // rope pair base
  const bf16* base = qkv + (size_t)r * (NSEG * NQKV) + c0;

  // K resident, rope'd
  float k[NSEG][12];
#pragma unroll
  for (int n = 0; n < NSEG; ++n) {
    union { uint2 u[3]; unsigned short s[12]; } K;
#pragma unroll
    for (int t = 0; t < 3; ++t)
      K.u[t] = *(const uint2*)(base + (size_t)n * NQKV + HID + 4 * t);
    const float* cp = fcos + n * (HID / 2) + j0;
    const float* sp = fsin + n * (HID / 2) + j0;
#pragma unroll
    for (int t = 0; t < 6; ++t) {
      const float cc = cp[t], ss = sp[t];
      const float e = b2f(K.s[2 * t]), f = b2f(K.s[2 * t + 1]);
      k[n][2 * t] = e * cc - f * ss;
      k[n][2 * t + 1] = e * ss + f * cc;
    }
  }

  // stream q one segment at a time; scores + 8-lane butterfly reduce
  float P[NSEG][NSEG];
#pragma unroll
  for (int n = 0; n < NSEG; ++n) {
    union { uint2 u[3]; unsigned short s[12]; } Q;
#pragma unroll
    for (int t = 0; t < 3; ++t)
      Q.u[t] = *(const uint2*)(base + (size_t)n * NQKV + 4 * t);
    const float* cp = fcos + n * (HID / 2) + j0;
    const float* sp = fsin + n * (HID / 2) + j0;
    float q[12];
#pragma unroll
    for (int t = 0; t < 6; ++t) {
      const float cc = cp[t], ss = sp[t];
      const float a = b2f(Q.s[2 * t]), b = b2f(Q.s[2 * t + 1]);
      q[2 * t] = a * cc - b * ss;
      q[2 * t + 1] = a * ss + b * cc;
    }
#pragma unroll
    for (int m = 0; m < NSEG; ++m) {
      float s = 0.f;
#pragma unroll
      for (int t = 0; t < 12; ++t) s += q[t] * k[m][t];
      s += __shfl_xor(s, 1, 64);
      s += __shfl_xor(s, 2, 64);
      s += __shfl_xor(s, 4, 64);
      P[n][m] = s * 0.10206207261596575f;  // 1/sqrt(96)
    }
  }

  // softmax over m (computed redundantly per lane)
#pragma unroll
  for (int n = 0; n < NSEG; ++n) {
    const float mx = fmaxf(fmaxf(P[n][0], P[n][1]), fmaxf(P[n][2], P[n][3]));
    float sum = 0.f;
#pragma unroll
    for (int m = 0; m < NSEG; ++m) {
      P[n][m] = __expf(P[n][m] - mx);
      sum += P[n][m];
    }
    const float inv = 1.f / sum;
#pragma unroll
    for (int m = 0; m < NSEG; ++m) P[n][m] *= inv;
  }

  // V, PV, pack bf16, store
  float v[NSEG][12];
#pragma unroll
  for (int n = 0; n < NSEG; ++n) {
    union { uint2 u[3]; unsigned short s[12]; } V;
#pragma unroll
    for (int t = 0; t < 3; ++t)
      V.u[t] = *(const uint2*)(base + (size_t)n * NQKV + 2 * HID + 4 * t);
#pragma unroll
    for (int t = 0; t < 12; ++t) v[n][t] = b2f(V.s[t]);
  }
  bf16* orow = obuf + (size_t)r * (NSEG * HID) + c0;
#pragma unroll
  for (int n = 0; n < NSEG; ++n) {
    union { uint2 u[3]; unsigned w[6]; } O;
#pragma unroll
    for (int t = 0; t < 6; ++t) {
      float o0 = 0.f, o1 = 0.f;
#pragma unroll
      for (int m = 0; m < NSEG; ++m) {
        o0 += P[n][m] * v[m][2 * t];
        o1 += P[n][m] * v[m][2 * t + 1];
      }
      O.w[t] = (unsigned)f2b(o0) | ((unsigned)f2b(o1) << 16);
    }
#pragma unroll
    for (int t = 0; t < 3; ++t)
      *(uint2*)(orow + (size_t)n * HID + 4 * t) = O.u[t];
  }
}

// ---------------------------------------------------------------------------
// GEMM2: out = O @ Wo + bo, fused scatter into (B,T,H,W,D) fp32 output.
//   A = obuf [32768][768] bf16, wT = Wo^T [1536][768] bf16. 8-phase 256x256.
//   (UNCHANGED from round 2 — control.)
// ---------------------------------------------------------------------------
__global__ __launch_bounds__(512, 2) void gemm_out(
    const bf16* __restrict__ Ao, const bf16* __restrict__ wT,
    const float* __restrict__ bo, float* __restrict__ out) {
  __shared__ __align__(16) char lds[131072];
  const int tid = threadIdx.x;
  const int lane = tid & 63, wave = tid >> 6;
  const int wr = wave >> 2, wc = wave & 3;
  const int l15 = lane & 15, quad = lane >> 4;

  // XCD-aware block swizzle: 768 blocks = 8 XCDs x 96
  const int lt = (blockIdx.x & 7) * 96 + (blockIdx.x >> 3);
  const int n0 = (lt % 6) * 256;
  const int m0 = (lt / 6) * 256;

  const int srow = wave * 16 + (lane >> 2);
  const int dswz = ((lane & 3) * 8) ^ ((lane & 32) >> 1);
  const bf16* asrc[2];
  const bf16* bsrc[2];
#pragma unroll
  for (int h = 0; h < 2; ++h) {
    asrc[h] = Ao + (size_t)(m0 + h * 128 + srow) * HID + dswz;
    bsrc[h] = wT + (size_t)(n0 + h * 128 + srow) * HID + dswz;
  }
  char* sdst = lds + wave * 1024;

#define STAGE_OA(kt, h) do {                                   \
    char* d_ = sdst + (((kt) & 1) * 65536) + (h) * 8192;       \
    const bf16* s_ = asrc[h] + (size_t)(kt) * 64;              \
    gload16(s_, d_);                                           \
    gload16(s_ + 32, d_ + 16384);                              \
  } while (0)
#define STAGE_OB(kt, h) do {                                   \
    char* d_ = sdst + 32768 + (((kt) & 1) * 65536) + (h) * 8192; \
    const bf16* s_ = bsrc[h] + (size_t)(kt) * 64;              \
    gload16(s_, d_);                                           \
    gload16(s_ + 32, d_ + 16384);                              \
  } while (0)

  const int lofs = l15 * 64 + ((quad * 16) ^ ((l15 & 8) << 2));
  const char* lA = lds + wr * 8192 + lofs;
  const char* lB = lds + 32768 + wc * 4096 + lofs;

  floatx4 acc[8][4] = {};
  short8 bfr[4][2];

  STAGE_OB(0, 0); STAGE_OB(0, 1); STAGE_OA(0, 0); STAGE_OA(0, 1);
  STAGE_OB(1, 0); STAGE_OB(1, 1);
  VM4;
  BARRIER;

  const int NKT = 12;
  for (int i = 0; i < 6; ++i) {
    const int a = 2 * i;
    PHASE(0, 0, 1, { STAGE_OA(a + 1, 0); }, {});
    PHASE(0, 1, 0, { STAGE_OA(a + 1, 1); }, {});
    PHASE(0, 2, 0, { if (a + 2 < NKT) STAGE_OB(a + 2, 0); }, {});
    PHASE(0, 3, 0, { if (a + 2 < NKT) STAGE_OB(a + 2, 1); },
          { if (a + 2 < NKT) VM4; else VM0; });
    PHASE(1, 0, 1, { if (a + 2 < NKT) STAGE_OA(a + 2, 0); }, {});
    PHASE(1, 1, 0, { if (a + 2 < NKT) STAGE_OA(a + 2, 1); }, {});
    PHASE(1, 2, 0, { if (a + 3 < NKT) STAGE_OB(a + 3, 0); }, {});
    PHASE(1, 3, 0, { if (a + 3 < NKT) STAGE_OB(a + 3, 1); },
          { if (a + 3 < NKT) VM4; else VM0; });
  }
#undef STAGE_OA
#undef STAGE_OB

  // epilogue: bias + scatter to (B,T,H,W,D) fp32: t = n*24+p
#pragma unroll
  for (int fm = 0; fm < 8; ++fm)
#pragma unroll
    for (int fn = 0; fn < 4; ++fn)
#pragma unroll
      for (int reg = 0; reg < 4; ++reg) {
        const int row = m0 + wr * 128 + fm * 16 + quad * 4 + reg;
        const int col = n0 + wc * 64 + fn * 16 + l15;
        const float v = acc[fm][fn][reg] + bo[col];
        const int r = row >> 2, n = row & 3;
        const int b = r >> 10, hw = r & 1023;
        const int p = col >> 6, d = col & 63;
        const size_t dst =
            ((size_t)((b * 96 + n * 24 + p) * 1024 + hw)) * 64 + d;
        out[dst] = v;
      }
}

// ---------------------------------------------------------------------------
extern "C" void kernel_launch(void* const* d_in, const int* in_sizes, int n_in,
                              void* d_out, int out_size, void* d_ws,
                              size_t ws_size, hipStream_t stream) {
  const float* x = (const float*)d_in[0];     // (8,96,32,32,64) fp32
  const float* fcos = (const float*)d_in[1];  // (4,384) fp32
  const float* fsin = (const float*)d_in[2];  // (4,384) fp32
  const float* Wq = (const float*)d_in[3];    // (1536,768) fp32
  const float* Wk = (const float*)d_in[4];
  const float* Wv = (const float*)d_in[5];
  const float* Wo = (const float*)d_in[6];    // (768,1536) fp32
  const float* bo = (const float*)d_in[7];    // (1536,) fp32
  float* out = (float*)d_out;                 // (8,96,32,32,64) fp32

  char* ws = (char*)d_ws;
  bf16* wqkvT = (bf16*)ws;                        // 2304*1536*2 = 7,077,888 B
  bf16* woT = (bf16*)(ws + 7077888);              // 1536*768*2  = 2,359,296 B
  bf16* qkv = (bf16*)(ws + 9437184);              // 32768*2304*2 = 150,994,944 B
  bf16* obuf = (bf16*)(ws + 160432128);           // 32768*768*2  = 50,331,648 B
  // xb (bf16 cast of x) lives in d_out scratch: its lifetime ends before
  // gemm_out, which overwrites every element of d_out.
  bf16* xb = (bf16*)d_out;

  transpose_all<<<dim3(48, 48, 4), dim3(32, 8), 0, stream>>>(
      Wq, Wk, Wv, Wo, wqkvT, woT);
  convert_x<<<12288, 256, 0, stream>>>(x, xb);
  gemm_qkv<<<1152, 512, 0, stream>>>(xb, wqkvT, qkv);
  attn_kernel<<<2048, 256, 0, stream>>>(qkv, fcos, fsin, obuf);
  gemm_out<<<768, 512, 0, stream>>>(obuf, woT, bo, out);
}